// Round 2
// baseline (425.469 us; speedup 1.0000x reference)
//
#include <hip/hip_runtime.h>

// ShiftConvGeneral: hard-softmax(3x3 weight) is one-hot -> depthwise conv
// collapses to a zero-padded shifted copy of x by (sh, sw) = argmax(|w|) - 1.
//
// x: (16,64,256,256) fp32 = 256 MiB in + 256 MiB out -> pure HBM streaming,
// floor ~85 us at 6.3 TB/s.
//
// Two kernels:
//   1. shift_prep: one thread computes (sh, sw) into d_ws.
//   2. shift_copy: 8192 blocks x 256 threads; each block moves 32 contiguous
//      rows (64 KB in/out). All loads/stores are aligned dwordx4; the +-1
//      column shift is realized with cross-lane shuffles instead of
//      misaligned scalar loads. No LDS, no barrier.

typedef float v4f __attribute__((ext_vector_type(4)));

__global__ void shift_prep_kernel(const float* __restrict__ w,
                                  int* __restrict__ shifts) {
    if (threadIdx.x == 0) {
        float best = -1.0f;
        int bi = 0;
#pragma unroll
        for (int i = 0; i < 9; ++i) {
            float a = fabsf(w[i]);
            if (a > best) { best = a; bi = i; }  // first max wins (jnp.argmax)
        }
        shifts[0] = bi / 3 - 1;  // row shift in {-1,0,1}
        shifts[1] = bi % 3 - 1;  // col shift in {-1,0,1}
    }
}

#define ROWS_PER_BLOCK 32

__global__ __launch_bounds__(256) void shift_copy_kernel(
    const float* __restrict__ x, const int* __restrict__ shifts,
    float* __restrict__ out) {
    const int sh = shifts[0];  // wave-uniform -> scalar loads
    const int sw = shifts[1];
    const int lane = threadIdx.x & 63;  // 64 lanes cover one 256-float row
    const int wid  = threadIdx.x >> 6;  // wave id 0..3

    const int block_row0 = blockIdx.x * ROWS_PER_BLOCK;  // global row index
    const int img = block_row0 >> 8;       // 32 | 256 -> block stays in 1 image
    const int h_base = block_row0 & 255;
    const float* __restrict__ xin  = x   + ((size_t)img << 16);
    float*       __restrict__ oimg = out + ((size_t)img << 16);

#pragma unroll
    for (int it = 0; it < ROWS_PER_BLOCK / 4; ++it) {
        const int h = h_base + it * 4 + wid;
        const int hin = h + sh;
        v4f v = {0.f, 0.f, 0.f, 0.f};
        if ((unsigned)hin < 256u) {  // wave-uniform branch
            const v4f* inq = (const v4f*)(xin + ((size_t)hin << 8));
            v4f q = __builtin_nontemporal_load(inq + lane);  // aligned 16B
            if (sw == 0) {
                v = q;
            } else if (sw == 1) {
                // out[c] = in[c+1]: {q.y,q.z,q.w, next lane's q.x}
                float nb = __shfl_down(q.x, 1);
                v.x = q.y; v.y = q.z; v.z = q.w;
                v.w = (lane == 63) ? 0.f : nb;   // col 256 -> pad 0
            } else {  // sw == -1
                // out[c] = in[c-1]: {prev lane's q.w, q.x,q.y,q.z}
                float nb = __shfl_up(q.w, 1);
                v.y = q.x; v.z = q.y; v.w = q.z;
                v.x = (lane == 0) ? 0.f : nb;    // col -1 -> pad 0
            }
        }
        __builtin_nontemporal_store(v, (v4f*)(oimg + ((size_t)h << 8)) + lane);
    }
}

extern "C" void kernel_launch(void* const* d_in, const int* in_sizes, int n_in,
                              void* d_out, int out_size, void* d_ws, size_t ws_size,
                              hipStream_t stream) {
    const float* x = (const float*)d_in[0];  // (16,64,256,256) fp32
    const float* w = (const float*)d_in[1];  // (1,1,3,3) fp32
    float* out = (float*)d_out;
    int* shifts = (int*)d_ws;

    shift_prep_kernel<<<1, 64, 0, stream>>>(w, shifts);

    const int total_rows = 16 * 64 * 256;               // 262144
    const int blocks = total_rows / ROWS_PER_BLOCK;     // 8192
    shift_copy_kernel<<<blocks, 256, 0, stream>>>(x, shifts, out);
}